// Round 9
// baseline (252.235 us; speedup 1.0000x reference)
//
#include <hip/hip_runtime.h>
#include <stdint.h>

typedef __bf16 bf16;
typedef _Float16 f16;
typedef __attribute__((ext_vector_type(4))) __bf16 bf16x4;
typedef __attribute__((ext_vector_type(8))) __bf16 bf16x8;
typedef __attribute__((ext_vector_type(8))) _Float16 f16x8;
typedef __attribute__((ext_vector_type(4))) float f32x4;
typedef __attribute__((ext_vector_type(2))) float f32x2;

constexpr int S = 2048;
constexpr int D = 1024;
constexpr int H = 16;
constexpr int DH = 64;
constexpr int M = 4096;  // B*S

constexpr float QSCALE = 0.18033688011112042f;  // 0.125 * log2(e)

// async global->LDS, 16B/lane; LDS dst = wave-uniform base + lane*16
__device__ __forceinline__ void async16(void* lds, const void* g) {
  __builtin_amdgcn_global_load_lds(
      (const __attribute__((address_space(1))) void*)g,
      (__attribute__((address_space(3))) void*)lds, 16, 0, 0);
}

// ===================== prep: maskbits + cvt3 + wtrans in one launch ==========
// blocks [0,16384): mask -> bitmask
// blocks [16384,28672): q,k,v fp32 -> bf16 (z = idx>>12)
// blocks [28672,29696): W [k][n] fp32 -> WT [n][k] bf16 (z==3: Wo -> fp16)
__global__ __launch_bounds__(256) void prep(
    const int* __restrict__ mask, uint64_t* __restrict__ MB,
    const float* __restrict__ q, const float* __restrict__ k,
    const float* __restrict__ v, bf16* __restrict__ qA, bf16* __restrict__ kA,
    bf16* __restrict__ vA, const float* __restrict__ Wq,
    const float* __restrict__ Wk, const float* __restrict__ Wv,
    const float* __restrict__ Wo, bf16* __restrict__ WTq,
    bf16* __restrict__ WTk, bf16* __restrict__ WTv, f16* __restrict__ WoT) {
  __shared__ float T[64 * 68];
  const int bid = blockIdx.x;
  const int tid = threadIdx.x;

  if (bid < 16384) {  // ---- maskbits ----
    const int gid = bid * 4 + (tid >> 6);
    const int lane = tid & 63;
    const int kt = gid >> 11;
    const int qq = gid & (S - 1);
    int mv = mask[(size_t)qq * S + kt * 64 + lane];
    uint64_t bits = __ballot(mv != 0);
    if (lane == 0) MB[(size_t)kt * S + qq] = bits;
    return;
  }

  if (bid < 28672) {  // ---- cvt3 ----
    const int idx = bid - 16384;
    const int z = idx >> 12;
    const int x = idx & 4095;
    const float* src = (z == 0) ? q : (z == 1) ? k : v;
    bf16* dst = (z == 0) ? qA : (z == 1) ? kA : vA;
    const size_t i = ((size_t)x * 256 + tid) * 4;
    f32x4 xv = *(const f32x4*)(src + i);
    bf16x4 o;
#pragma unroll
    for (int j = 0; j < 4; j++) o[j] = (bf16)xv[j];
    *(bf16x4*)(dst + i) = o;
    return;
  }

  // ---- wtrans ----
  const int idx = bid - 28672;  // 0..1023
  const int z = idx >> 8;
  const int xy = idx & 255;
  const int n0 = (xy >> 4) * 64, k0 = (xy & 15) * 64;
  const float* W = (z == 0) ? Wq : (z == 1) ? Wk : (z == 2) ? Wv : Wo;
  const int lr = tid >> 4, lc = (tid & 15) * 4;
#pragma unroll
  for (int r = 0; r < 4; r++) {
    f32x4 vv = *(const f32x4*)(W + (size_t)(k0 + r * 16 + lr) * 1024 + n0 + lc);
    *(f32x4*)&T[(r * 16 + lr) * 68 + lc] = vv;
  }
  __syncthreads();
  const int nn = tid >> 3, kc = (tid & 7) * 8;
#pragma unroll
  for (int p = 0; p < 2; p++) {
    int n = p * 32 + nn;
    if (z < 3) {
      bf16x8 h;
#pragma unroll
      for (int j = 0; j < 8; j++) h[j] = (bf16)T[(kc + j) * 68 + n];
      bf16* WT = (z == 0) ? WTq : (z == 1) ? WTk : WTv;
      *(bf16x8*)(WT + (size_t)(n0 + n) * 1024 + k0 + kc) = h;
    } else {
      f16x8 hf;
#pragma unroll
      for (int j = 0; j < 8; j++) hf[j] = (f16)T[(kc + j) * 68 + n];
      *(f16x8*)(WoT + (size_t)(n0 + n) * 1024 + k0 + kc) = hf;
    }
  }
}

// ===================== fused QKV GEMM: BK=64, XOR swizzle =====================
// Tiles 128 rows x 128B; phys granule = g ^ (row&7) -> 2-way free on reads.
// z=0: Q*QSCALE -> bf16 [m][D] (GEMM-natural); z=1: K [m][D]; z=2: V^T [B*H,DH,S]
// Q/K direct-store epilogue: attn reads per-head 64-elem segments, which stay
// contiguous in [m][D], so no transpose pass is needed (row m = b*2048+s).
__global__ __launch_bounds__(256) void gemm_qkv(
    const bf16* __restrict__ Aq, const bf16* __restrict__ Ak,
    const bf16* __restrict__ Av, const bf16* __restrict__ WTq,
    const bf16* __restrict__ WTk, const bf16* __restrict__ WTv,
    const float* __restrict__ bq, const float* __restrict__ bk,
    const float* __restrict__ bv, bf16* __restrict__ Qb,
    bf16* __restrict__ Kb, bf16* __restrict__ VT) {
  __shared__ char smem[32768];  // A [0,16K) B [16K,32K)

  const int z = blockIdx.z;
  const bf16* A = (z == 0) ? Aq : (z == 1) ? Ak : Av;
  const bf16* WT = (z == 0) ? WTq : (z == 1) ? WTk : WTv;
  const float* bias = (z == 0) ? bq : (z == 1) ? bk : bv;
  const float oscale = (z == 0) ? QSCALE : 1.0f;

  const int tid = threadIdx.x;
  const int bn = blockIdx.x * 128;
  const int bm = blockIdx.y * 128;
  const int wv = tid >> 6;
  const int lane = tid & 63;
  const int quad = lane >> 4;
  const int lo = lane & 15;
  const int wm = (wv >> 1) * 64;
  const int wn = (wv & 1) * 64;

  f32x4 acc[4][4];
#pragma unroll
  for (int i = 0; i < 4; i++)
#pragma unroll
    for (int j = 0; j < 4; j++) acc[i][j] = {0.f, 0.f, 0.f, 0.f};

  const int rloc = lane >> 3;              // staging: row within 8-row chunk
  const int gx = (lane & 7) ^ rloc;        // staging: global granule (xor swz)
  const int rx = (lo & 7);                 // read swizzle key

  for (int kt = 0; kt < 16; ++kt) {
#pragma unroll
    for (int j = 0; j < 4; j++) {
      int ch = wv * 4 + j;  // 0..15, 8 rows each
      async16(smem + ch * 1024,
              A + (size_t)(bm + ch * 8 + rloc) * 1024 + kt * 64 + gx * 8);
      async16(smem + 16384 + ch * 1024,
              WT + (size_t)(bn + ch * 8 + rloc) * 1024 + kt * 64 + gx * 8);
    }
    __syncthreads();

#pragma unroll
    for (int ks = 0; ks < 2; ks++) {
      bf16x8 af[4], bfr[4];
#pragma unroll
      for (int mi = 0; mi < 4; mi++)
        af[mi] = *(const bf16x8*)(smem + (wm + mi * 16 + lo) * 128 +
                                  (((ks * 4 + quad) ^ rx) * 16));
#pragma unroll
      for (int ni = 0; ni < 4; ni++)
        bfr[ni] = *(const bf16x8*)(smem + 16384 + (wn + ni * 16 + lo) * 128 +
                                   (((ks * 4 + quad) ^ rx) * 16));
#pragma unroll
      for (int mi = 0; mi < 4; mi++)
#pragma unroll
        for (int ni = 0; ni < 4; ni++)
          acc[mi][ni] = __builtin_amdgcn_mfma_f32_16x16x32_bf16(
              af[mi], bfr[ni], acc[mi][ni], 0, 0, 0);
    }
    __syncthreads();
  }

  if (z == 2) {  // V^T: direct bf16x4 stores [bh][dh][s]
    const int b = bm >> 11;
    const int srow0 = bm & (S - 1);
#pragma unroll
    for (int mi = 0; mi < 4; mi++)
#pragma unroll
      for (int ni = 0; ni < 4; ni++) {
        int col = bn + wn + ni * 16 + lo;
        int h = col >> 6, dh = col & 63;
        float bvv = bias[col];
        bf16x4 t;
#pragma unroll
        for (int r = 0; r < 4; r++) t[r] = (bf16)(acc[mi][ni][r] + bvv);
        int s0 = srow0 + wm + mi * 16 + quad * 4;
        *(bf16x4*)&VT[(((size_t)(b * H + h)) * DH + dh) * S + s0] = t;
      }
    return;
  }

  // Q/K: direct GEMM-natural [m][D] stores (no transpose pass)
  bf16* out = (z == 0) ? Qb : Kb;
#pragma unroll
  for (int mi = 0; mi < 4; mi++)
#pragma unroll
    for (int ni = 0; ni < 4; ni++) {
      int col = bn + wn + ni * 16 + lo;
      float bvv = bias[col];
#pragma unroll
      for (int r = 0; r < 4; r++) {
        int row = bm + wm + mi * 16 + quad * 4 + r;
        out[(size_t)row * 1024 + col] = (bf16)((acc[mi][ni][r] + bvv) * oscale);
      }
    }
}

// ===================== O-projection: fp16 GEMM, 64x128 tiles, 2 blocks/CU ======
// grid (8,64) = 512 blocks, 4 waves. A-tile 64 rows (8 chunks), B-tile 128 rows
// (16 chunks); per wave 2 A + 4 B chunks. Same XOR swizzle/read paths as before.
__global__ __launch_bounds__(256) void gemm_o(
    const f16* __restrict__ A, const f16* __restrict__ WT,
    const float* __restrict__ bias, float* __restrict__ out) {
  __shared__ char smem[24576];  // A [0,8K) B [8K,24K)

  const int tid = threadIdx.x;
  const int bn = blockIdx.x * 128;
  const int bm = blockIdx.y * 64;
  const int wv = tid >> 6;
  const int lane = tid & 63;
  const int quad = lane >> 4;
  const int lo = lane & 15;
  const int wm = (wv >> 1) * 32;
  const int wn = (wv & 1) * 64;

  f32x4 acc[2][4];
#pragma unroll
  for (int i = 0; i < 2; i++)
#pragma unroll
    for (int j = 0; j < 4; j++) acc[i][j] = {0.f, 0.f, 0.f, 0.f};

  const int rloc = lane >> 3;
  const int gx = (lane & 7) ^ rloc;
  const int rx = (lo & 7);

  for (int kt = 0; kt < 16; ++kt) {
#pragma unroll
    for (int j = 0; j < 2; j++) {  // A: 8 chunks of 8 rows
      int ch = wv * 2 + j;
      async16(smem + ch * 1024,
              A + (size_t)(bm + ch * 8 + rloc) * 1024 + kt * 64 + gx * 8);
    }
#pragma unroll
    for (int j = 0; j < 4; j++) {  // B: 16 chunks of 8 rows
      int ch = wv * 4 + j;
      async16(smem + 8192 + ch * 1024,
              WT + (size_t)(bn + ch * 8 + rloc) * 1024 + kt * 64 + gx * 8);
    }
    __syncthreads();

#pragma unroll
    for (int ks = 0; ks < 2; ks++) {
      f16x8 af[2], bfr[4];
#pragma unroll
      for (int mi = 0; mi < 2; mi++)
        af[mi] = *(const f16x8*)(smem + (wm + mi * 16 + lo) * 128 +
                                 (((ks * 4 + quad) ^ rx) * 16));
#pragma unroll
      for (int ni = 0; ni < 4; ni++)
        bfr[ni] = *(const f16x8*)(smem + 8192 + (wn + ni * 16 + lo) * 128 +
                                  (((ks * 4 + quad) ^ rx) * 16));
#pragma unroll
      for (int mi = 0; mi < 2; mi++)
#pragma unroll
        for (int ni = 0; ni < 4; ni++)
          acc[mi][ni] = __builtin_amdgcn_mfma_f32_16x16x32_f16(
              af[mi], bfr[ni], acc[mi][ni], 0, 0, 0);
    }
    __syncthreads();
  }

#pragma unroll
  for (int mi = 0; mi < 2; mi++)
#pragma unroll
    for (int ni = 0; ni < 4; ni++) {
      int col = bn + wn + ni * 16 + lo;
      float bvv = bias[col];
#pragma unroll
      for (int r = 0; r < 4; r++) {
        int row = bm + wm + mi * 16 + quad * 4 + r;
        out[(size_t)row * 1024 + col] = acc[mi][ni][r] + bvv;
      }
    }
}

// ===================== attention: 8 waves, dbuf K/V, 1 barrier/kt ============
// Round-7 verified structure (serial SM then PV); Q/K now read from
// GEMM-natural [m][D] layout: head segment = m*1024 + h*64 + (0..63).
__global__ __launch_bounds__(512) void attn_kernel(
    const bf16* __restrict__ Qg, const bf16* __restrict__ Kg,
    const bf16* __restrict__ VTg, const uint64_t* __restrict__ MB,
    f16* __restrict__ AO) {
  __shared__ char smem[49152];

  const int tid = threadIdx.x;
  const int wv = tid >> 6;  // 0..7
  const int lane = tid & 63;
  const int quad = lane >> 4;
  const int lo = lane & 15;

  const int lin = blockIdx.x;  // 512 blocks
  const int bh = (lin & 7) * 4 + ((lin >> 3) & 3);  // XCD-local K/V set
  const int qt = lin >> 5;                          // 0..15
  const int qbase = qt * 128 + wv * 16;
  const int b = bh >> 4, h = bh & (H - 1);
  const size_t vbase = (size_t)bh * S * DH;      // V^T layout [bh][dh][s]
  const int hcol = h * 64;                       // Q/K head column offset
  bf16* Pw = (bf16*)(smem + 32768 + wv * 2048);  // [16][64] bf16
  const int xm = (lo & 7) << 1;                  // P-swizzle (8B granules)

  // staging constants: 16 chunks of 1KB (8 K + 8 V), 2 per wave
  const int c0 = wv * 2;
  const int rloc = lane >> 3;
  const int gx = (lane & 7) ^ rloc;
  const int rx = lo & 7;  // read swizzle key

  // Q B-frags: 16 q-rows for this wave ([m][D] layout)
  bf16x8 qf[2];
  {
    const bf16* qp =
        Qg + (size_t)(b * S + qbase + lo) * 1024 + hcol + quad * 8;
    qf[0] = *(const bf16x8*)qp;
    qf[1] = *(const bf16x8*)(qp + 32);
  }

  f32x4 Oacc[4];
#pragma unroll
  for (int j = 0; j < 4; j++) Oacc[j] = {0.f, 0.f, 0.f, 0.f};
  f32x2 lp = {0.f, 0.f};

#define STAGE(kt_, buf_)                                                       \
  {                                                                            \
    _Pragma("unroll") for (int j = 0; j < 2; j++) {                            \
      int c = c0 + j;                                                          \
      if (c < 8) {                                                             \
        async16((buf_) + c * 1024,                                             \
                Kg + (size_t)(b * S + (kt_)*64 + c * 8 + rloc) * 1024 + hcol + \
                    gx * 8);                                                   \
      } else {                                                                 \
        int cv = c - 8;                                                        \
        async16((buf_) + 8192 + cv * 1024,                                     \
                VTg + vbase + (size_t)(cv * 8 + rloc) * S + (kt_)*64 + gx * 8); \
      }                                                                        \
    }                                                                          \
  }

  STAGE(0, smem);
  uint64_t mcur = MB[(size_t)0 * S + qbase + lo];  // prefetched mask word

  for (int kt = 0; kt < 32; ++kt) {
    const char* cur = smem + (kt & 1) * 16384;

    uint64_t m0 = mcur >> (quad * 4);
    uint32_t mw[2] = {(uint32_t)m0, (uint32_t)(m0 >> 32)};

    __syncthreads();  // publishes stage(kt); drains loads issued last iter
    if (kt + 1 < 32) {
      STAGE(kt + 1, smem + ((kt + 1) & 1) * 16384);
      mcur = MB[(size_t)(kt + 1) * S + qbase + lo];  // hidden under compute
    }

    const char* Kls = cur;
    const char* Vls = cur + 8192;

    // S^T = K Q^T
    f32x4 sacc[4];
#pragma unroll
    for (int mi = 0; mi < 4; mi++) sacc[mi] = {0.f, 0.f, 0.f, 0.f};
    __builtin_amdgcn_s_setprio(1);
#pragma unroll
    for (int mi = 0; mi < 4; mi++) {
      bf16x8 k0 = *(const bf16x8*)(Kls + (mi * 16 + lo) * 128 + ((quad ^ rx) * 16));
      bf16x8 k1 = *(const bf16x8*)(Kls + (mi * 16 + lo) * 128 + (((4 + quad) ^ rx) * 16));
      sacc[mi] = __builtin_amdgcn_mfma_f32_16x16x32_bf16(k0, qf[0], sacc[mi], 0, 0, 0);
      sacc[mi] = __builtin_amdgcn_mfma_f32_16x16x32_bf16(k1, qf[1], sacc[mi], 0, 0, 0);
    }
    __builtin_amdgcn_s_setprio(0);

    // p = bit ? exp2(s) : 0 via AND with sign-extended bit (bit-identical,
    // v_bfe_i32+v_and = 2 ops vs bfe+cmp+cndmask = 3); pk-add row sums.
#pragma unroll
    for (int mi = 0; mi < 4; mi++) {
      bf16x4 t;
#pragma unroll
      for (int r = 0; r < 4; r++) {
        float p = __builtin_amdgcn_exp2f(sacc[mi][r]);
        int ext = __builtin_amdgcn_sbfe((int)mw[mi >> 1], ((mi & 1) << 4) + r, 1);
        p = __builtin_bit_cast(float, __builtin_bit_cast(int, p) & ext);
        lp[r & 1] += p;
        t[r] = (bf16)p;
      }
      *(bf16x4*)&Pw[lo * 64 + (((mi * 4 + quad) ^ xm) * 4)] = t;
    }

    // O += P V
    __builtin_amdgcn_s_setprio(1);
#pragma unroll
    for (int kk = 0; kk < 2; kk++) {
      int g16 = kk * 8 + quad * 2;
      bf16x8 pa = *(const bf16x8*)&Pw[lo * 64 + ((g16 ^ xm) * 4)];
#pragma unroll
      for (int ni = 0; ni < 4; ni++) {
        bf16x8 vb = *(const bf16x8*)(Vls + (ni * 16 + lo) * 128 +
                                     (((kk * 4 + quad) ^ rx) * 16));
        Oacc[ni] = __builtin_amdgcn_mfma_f32_16x16x32_bf16(pa, vb, Oacc[ni], 0, 0, 0);
      }
    }
    __builtin_amdgcn_s_setprio(0);
  }
#undef STAGE

  // finish row-sums across quads (keys split 4/quad per mi)
  float lpart = lp[0] + lp[1];
  lpart += __shfl_xor(lpart, 16);
  lpart += __shfl_xor(lpart, 32);

#pragma unroll
  for (int r = 0; r < 4; r++) {
    float inv = 1.0f / __shfl(lpart, quad * 4 + r);
    int q = qbase + quad * 4 + r;
    size_t rowoff = (size_t)(b * S + q) * D + h * DH;
#pragma unroll
    for (int ni = 0; ni < 4; ni++)
      AO[rowoff + ni * 16 + lo] = (f16)(Oacc[ni][r] * inv);
  }
}

// ===================== launch =====================
extern "C" void kernel_launch(void* const* d_in, const int* in_sizes, int n_in,
                              void* d_out, int out_size, void* d_ws,
                              size_t ws_size, hipStream_t stream) {
  const float* q = (const float*)d_in[0];
  const float* k = (const float*)d_in[1];
  const float* v = (const float*)d_in[2];
  const int* mask = (const int*)d_in[3];
  const float* w_q = (const float*)d_in[4];
  const float* b_q = (const float*)d_in[5];
  const float* w_k = (const float*)d_in[6];
  const float* b_k = (const float*)d_in[7];
  const float* w_v = (const float*)d_in[8];
  const float* b_v = (const float*)d_in[9];
  const float* w_o = (const float*)d_in[10];
  const float* b_o = (const float*)d_in[11];

  // ws (MiB offsets):
  // [0,8) Qb | [8,16) Kb | [16,24) VT | [24,32) qA | [32,40) kA | [40,48) vA
  // [48,50) WTq | [50,52) WTk | [52,54) WTv | [54,56) WoT(f16) | [58,58.5) MB
  // overlays: AO(f16)=[24,32) (after gemm_qkv consumes qA)
  char* w = (char*)d_ws;
  const size_t MiB = 1ull << 20;
  bf16* Qb = (bf16*)w;
  bf16* Kb = (bf16*)(w + 8 * MiB);
  bf16* VT = (bf16*)(w + 16 * MiB);
  bf16* qA = (bf16*)(w + 24 * MiB);
  bf16* kA = (bf16*)(w + 32 * MiB);
  bf16* vA = (bf16*)(w + 40 * MiB);
  f16* AO = (f16*)(w + 24 * MiB);
  bf16* WTq = (bf16*)(w + 48 * MiB);
  bf16* WTk = (bf16*)(w + 50 * MiB);
  bf16* WTv = (bf16*)(w + 52 * MiB);
  f16* WoT = (f16*)(w + 54 * MiB);
  uint64_t* MBits = (uint64_t*)(w + 58 * MiB);

  prep<<<29696, 256, 0, stream>>>(mask, MBits, q, k, v, qA, kA, vA, w_q, w_k,
                                  w_v, w_o, WTq, WTk, WTv, WoT);
  gemm_qkv<<<dim3(8, 32, 3), 256, 0, stream>>>(qA, kA, vA, WTq, WTk, WTv, b_q,
                                               b_k, b_v, Qb, Kb, VT);
  attn_kernel<<<dim3(512), 512, 0, stream>>>(Qb, Kb, VT, MBits, AO);
  gemm_o<<<dim3(8, 64), 256, 0, stream>>>(AO, WoT, b_o, (float*)d_out);
}

// Round 11
// 248.124 us; speedup vs baseline: 1.0166x; 1.0166x over previous
//
#include <hip/hip_runtime.h>
#include <stdint.h>

typedef __bf16 bf16;
typedef _Float16 f16;
typedef __attribute__((ext_vector_type(4))) __bf16 bf16x4;
typedef __attribute__((ext_vector_type(8))) __bf16 bf16x8;
typedef __attribute__((ext_vector_type(8))) _Float16 f16x8;
typedef __attribute__((ext_vector_type(4))) float f32x4;
typedef __attribute__((ext_vector_type(2))) float f32x2;

constexpr int S = 2048;
constexpr int D = 1024;
constexpr int H = 16;
constexpr int DH = 64;
constexpr int M = 4096;  // B*S

constexpr float QSCALE = 0.18033688011112042f;  // 0.125 * log2(e)

// async global->LDS, 16B/lane; LDS dst = wave-uniform base + lane*16
__device__ __forceinline__ void async16(void* lds, const void* g) {
  __builtin_amdgcn_global_load_lds(
      (const __attribute__((address_space(1))) void*)g,
      (__attribute__((address_space(3))) void*)lds, 16, 0, 0);
}

// ===================== prep: maskbits + cvt3 + wtrans in one launch ==========
// blocks [0,16384): mask -> bitmask
// blocks [16384,28672): q,k,v fp32 -> bf16 (z = idx>>12)
// blocks [28672,29696): W [k][n] fp32 -> WT [n][k] bf16 (z==3: Wo -> fp16)
__global__ __launch_bounds__(256) void prep(
    const int* __restrict__ mask, uint64_t* __restrict__ MB,
    const float* __restrict__ q, const float* __restrict__ k,
    const float* __restrict__ v, bf16* __restrict__ qA, bf16* __restrict__ kA,
    bf16* __restrict__ vA, const float* __restrict__ Wq,
    const float* __restrict__ Wk, const float* __restrict__ Wv,
    const float* __restrict__ Wo, bf16* __restrict__ WTq,
    bf16* __restrict__ WTk, bf16* __restrict__ WTv, f16* __restrict__ WoT) {
  __shared__ float T[64 * 68];
  const int bid = blockIdx.x;
  const int tid = threadIdx.x;

  if (bid < 16384) {  // ---- maskbits ----
    const int gid = bid * 4 + (tid >> 6);
    const int lane = tid & 63;
    const int kt = gid >> 11;
    const int qq = gid & (S - 1);
    int mv = mask[(size_t)qq * S + kt * 64 + lane];
    uint64_t bits = __ballot(mv != 0);
    if (lane == 0) MB[(size_t)kt * S + qq] = bits;
    return;
  }

  if (bid < 28672) {  // ---- cvt3 ----
    const int idx = bid - 16384;
    const int z = idx >> 12;
    const int x = idx & 4095;
    const float* src = (z == 0) ? q : (z == 1) ? k : v;
    bf16* dst = (z == 0) ? qA : (z == 1) ? kA : vA;
    const size_t i = ((size_t)x * 256 + tid) * 4;
    f32x4 xv = *(const f32x4*)(src + i);
    bf16x4 o;
#pragma unroll
    for (int j = 0; j < 4; j++) o[j] = (bf16)xv[j];
    *(bf16x4*)(dst + i) = o;
    return;
  }

  // ---- wtrans ----
  const int idx = bid - 28672;  // 0..1023
  const int z = idx >> 8;
  const int xy = idx & 255;
  const int n0 = (xy >> 4) * 64, k0 = (xy & 15) * 64;
  const float* W = (z == 0) ? Wq : (z == 1) ? Wk : (z == 2) ? Wv : Wo;
  const int lr = tid >> 4, lc = (tid & 15) * 4;
#pragma unroll
  for (int r = 0; r < 4; r++) {
    f32x4 vv = *(const f32x4*)(W + (size_t)(k0 + r * 16 + lr) * 1024 + n0 + lc);
    *(f32x4*)&T[(r * 16 + lr) * 68 + lc] = vv;
  }
  __syncthreads();
  const int nn = tid >> 3, kc = (tid & 7) * 8;
#pragma unroll
  for (int p = 0; p < 2; p++) {
    int n = p * 32 + nn;
    if (z < 3) {
      bf16x8 h;
#pragma unroll
      for (int j = 0; j < 8; j++) h[j] = (bf16)T[(kc + j) * 68 + n];
      bf16* WT = (z == 0) ? WTq : (z == 1) ? WTk : WTv;
      *(bf16x8*)(WT + (size_t)(n0 + n) * 1024 + k0 + kc) = h;
    } else {
      f16x8 hf;
#pragma unroll
      for (int j = 0; j < 8; j++) hf[j] = (f16)T[(kc + j) * 68 + n];
      *(f16x8*)(WoT + (size_t)(n0 + n) * 1024 + k0 + kc) = hf;
    }
  }
}

// ===================== fused QKV GEMM: BK=32 dbuf prefetch, pair-interleave ====
// 128x128 tile, 32 kt of BK=32. LDS dbuf 2x16KB (A 8K | B 8K per buf); one
// __syncthreads per kt, STAGE(kt+1) issued after the barrier so loads fly
// under compute(kt) (attn's verified loop pattern). Staging/read swizzle is
// gemm_o's verified pair-interleave: rows paired into 128B lines, unit
// u = ((g^((r>>1)&3))<<1)|(r&1). Same K-order per acc chain as BK=64 version
// -> bit-identical results.
// z=0: Q*QSCALE -> bf16 [bh][s][dh]; z=1: K; z=2: V^T [B*H,DH,S]
__global__ __launch_bounds__(256) void gemm_qkv(
    const bf16* __restrict__ Aq, const bf16* __restrict__ Ak,
    const bf16* __restrict__ Av, const bf16* __restrict__ WTq,
    const bf16* __restrict__ WTk, const bf16* __restrict__ WTv,
    const float* __restrict__ bq, const float* __restrict__ bk,
    const float* __restrict__ bv, bf16* __restrict__ Qb,
    bf16* __restrict__ Kb, bf16* __restrict__ VT) {
  __shared__ char smem[34816];  // dbuf [0,32K); epilogue T overlay 34816B

  const int z = blockIdx.z;
  const bf16* A = (z == 0) ? Aq : (z == 1) ? Ak : Av;
  const bf16* WT = (z == 0) ? WTq : (z == 1) ? WTk : WTv;
  const float* bias = (z == 0) ? bq : (z == 1) ? bk : bv;
  const float oscale = (z == 0) ? QSCALE : 1.0f;

  const int tid = threadIdx.x;
  const int bn = blockIdx.x * 128;
  const int bm = blockIdx.y * 128;
  const int wv = tid >> 6;
  const int lane = tid & 63;
  const int quad = lane >> 4;
  const int lo = lane & 15;
  const int wm4 = (wv >> 1) * 4096;  // A row-block byte offset (64 rows)
  const int wn4 = (wv & 1) * 4096;   // B row-block byte offset

  f32x4 acc[4][4];
#pragma unroll
  for (int i = 0; i < 4; i++)
#pragma unroll
    for (int j = 0; j < 4; j++) acc[i][j] = {0.f, 0.f, 0.f, 0.f};

  // pair-interleave staging (chunk = 16 rows = 8 pairs = 1KB)
  const int pl = lane >> 3;            // pair within chunk
  const int uu = lane & 7;             // 16B unit within 128B pair line
  const int srow = pl * 2 + (uu & 1);  // logical row in chunk
  const int sg = (uu >> 1) ^ (pl & 3); // logical granule fetched
  // frag-read: row = base16 + lo, granule = quad
  const int uread = (((quad ^ ((lo >> 1) & 3)) << 1) | (lo & 1)) * 16;
  const int aoff = (lo >> 1) * 128 + uread;

#define QSTAGE(kt_, buf_)                                                      \
  {                                                                            \
    _Pragma("unroll") for (int j = 0; j < 4; j++) {                            \
      int c = wv * 4 + j; /* 0..15: 8 A-chunks then 8 B-chunks */              \
      if (c < 8) {                                                             \
        async16((buf_) + c * 1024,                                             \
                A + (size_t)(bm + c * 16 + srow) * 1024 + (kt_)*32 + sg * 8);  \
      } else {                                                                 \
        int cb = c - 8;                                                        \
        async16((buf_) + 8192 + cb * 1024,                                     \
                WT + (size_t)(bn + cb * 16 + srow) * 1024 + (kt_)*32 + sg * 8);\
      }                                                                        \
    }                                                                          \
  }

  QSTAGE(0, smem);

  for (int kt = 0; kt < 32; ++kt) {
    const char* cur = smem + (kt & 1) * 16384;
    __syncthreads();  // publishes stage(kt); drains loads issued last iter
    if (kt + 1 < 32) QSTAGE(kt + 1, smem + ((kt + 1) & 1) * 16384);

    bf16x8 af[4], bfr[4];
#pragma unroll
    for (int mi = 0; mi < 4; mi++)
      af[mi] = *(const bf16x8*)(cur + wm4 + mi * 1024 + aoff);
#pragma unroll
    for (int ni = 0; ni < 4; ni++)
      bfr[ni] = *(const bf16x8*)(cur + 8192 + wn4 + ni * 1024 + aoff);
#pragma unroll
    for (int mi = 0; mi < 4; mi++)
#pragma unroll
      for (int ni = 0; ni < 4; ni++)
        acc[mi][ni] = __builtin_amdgcn_mfma_f32_16x16x32_bf16(
            af[mi], bfr[ni], acc[mi][ni], 0, 0, 0);
  }
#undef QSTAGE

  const int b = bm >> 11;
  const int srow0 = bm & (S - 1);
  const int wm = (wv >> 1) * 64;
  const int wn = (wv & 1) * 64;

  if (z == 2) {  // V^T: direct bf16x4 stores [bh][dh][s]
#pragma unroll
    for (int mi = 0; mi < 4; mi++)
#pragma unroll
      for (int ni = 0; ni < 4; ni++) {
        int col = bn + wn + ni * 16 + lo;
        int h = col >> 6, dh = col & 63;
        float bvv = bias[col];
        bf16x4 t;
#pragma unroll
        for (int r = 0; r < 4; r++) t[r] = (bf16)(acc[mi][ni][r] + bvv);
        int s0 = srow0 + wm + mi * 16 + quad * 4;
        *(bf16x4*)&VT[(((size_t)(b * H + h)) * DH + dh) * S + s0] = t;
      }
    return;
  }

  // Q/K: LDS transpose -> coalesced [bh][s][dh] stores
  __syncthreads();  // all waves done reading dbuf before T overlay
  bf16* T = (bf16*)smem;  // [128][136]
#pragma unroll
  for (int mi = 0; mi < 4; mi++)
#pragma unroll
    for (int ni = 0; ni < 4; ni++) {
      int col = wn + ni * 16 + lo;
      float bvv = bias[bn + col];
#pragma unroll
      for (int r = 0; r < 4; r++) {
        int row = wm + mi * 16 + quad * 4 + r;
        T[row * 136 + col] = (bf16)((acc[mi][ni][r] + bvv) * oscale);
      }
    }
  __syncthreads();
  bf16* out = (z == 0) ? Qb : Kb;
  const int rr = tid >> 1;
  const int half = tid & 1;
  const int h = (bn >> 6) + half;
  bf16* gp = out + (((size_t)(b * H + h)) * S + srow0 + rr) * DH;
#pragma unroll
  for (int j = 0; j < 8; j++)
    *(bf16x8*)(gp + j * 8) = *(const bf16x8*)&T[rr * 136 + half * 64 + j * 8];
}

// ===================== O-projection: fp16 GEMM, 64x128 tiles, 2 blocks/CU ======
// grid (8,64) = 512 blocks, 4 waves. A-tile 64 rows (8 chunks), B-tile 128 rows
// (16 chunks); per wave 2 A + 4 B chunks. Same XOR swizzle/read paths as before.
__global__ __launch_bounds__(256) void gemm_o(
    const f16* __restrict__ A, const f16* __restrict__ WT,
    const float* __restrict__ bias, float* __restrict__ out) {
  __shared__ char smem[24576];  // A [0,8K) B [8K,24K)

  const int tid = threadIdx.x;
  const int bn = blockIdx.x * 128;
  const int bm = blockIdx.y * 64;
  const int wv = tid >> 6;
  const int lane = tid & 63;
  const int quad = lane >> 4;
  const int lo = lane & 15;
  const int wm = (wv >> 1) * 32;
  const int wn = (wv & 1) * 64;

  f32x4 acc[2][4];
#pragma unroll
  for (int i = 0; i < 2; i++)
#pragma unroll
    for (int j = 0; j < 4; j++) acc[i][j] = {0.f, 0.f, 0.f, 0.f};

  const int rloc = lane >> 3;
  const int gx = (lane & 7) ^ rloc;
  const int rx = (lo & 7);

  for (int kt = 0; kt < 16; ++kt) {
#pragma unroll
    for (int j = 0; j < 2; j++) {  // A: 8 chunks of 8 rows
      int ch = wv * 2 + j;
      async16(smem + ch * 1024,
              A + (size_t)(bm + ch * 8 + rloc) * 1024 + kt * 64 + gx * 8);
    }
#pragma unroll
    for (int j = 0; j < 4; j++) {  // B: 16 chunks of 8 rows
      int ch = wv * 4 + j;
      async16(smem + 8192 + ch * 1024,
              WT + (size_t)(bn + ch * 8 + rloc) * 1024 + kt * 64 + gx * 8);
    }
    __syncthreads();

#pragma unroll
    for (int ks = 0; ks < 2; ks++) {
      f16x8 af[2], bfr[4];
#pragma unroll
      for (int mi = 0; mi < 2; mi++)
        af[mi] = *(const f16x8*)(smem + (wm + mi * 16 + lo) * 128 +
                                 (((ks * 4 + quad) ^ rx) * 16));
#pragma unroll
      for (int ni = 0; ni < 4; ni++)
        bfr[ni] = *(const f16x8*)(smem + 8192 + (wn + ni * 16 + lo) * 128 +
                                  (((ks * 4 + quad) ^ rx) * 16));
#pragma unroll
      for (int mi = 0; mi < 2; mi++)
#pragma unroll
        for (int ni = 0; ni < 4; ni++)
          acc[mi][ni] = __builtin_amdgcn_mfma_f32_16x16x32_f16(
              af[mi], bfr[ni], acc[mi][ni], 0, 0, 0);
    }
    __syncthreads();
  }

#pragma unroll
  for (int mi = 0; mi < 2; mi++)
#pragma unroll
    for (int ni = 0; ni < 4; ni++) {
      int col = bn + wn + ni * 16 + lo;
      float bvv = bias[col];
#pragma unroll
      for (int r = 0; r < 4; r++) {
        int row = bm + wm + mi * 16 + quad * 4 + r;
        out[(size_t)row * 1024 + col] = acc[mi][ni][r] + bvv;
      }
    }
}

// ===================== attention: 8 waves, dbuf K/V, 1 barrier/kt ============
// Round-7 verified structure: [bh][s][dh] Q/K reads, serial SM then PV.
__global__ __launch_bounds__(512) void attn_kernel(
    const bf16* __restrict__ Qg, const bf16* __restrict__ Kg,
    const bf16* __restrict__ VTg, const uint64_t* __restrict__ MB,
    f16* __restrict__ AO) {
  __shared__ char smem[49152];

  const int tid = threadIdx.x;
  const int wv = tid >> 6;  // 0..7
  const int lane = tid & 63;
  const int quad = lane >> 4;
  const int lo = lane & 15;

  const int lin = blockIdx.x;  // 512 blocks
  const int bh = (lin & 7) * 4 + ((lin >> 3) & 3);  // XCD-local K/V set
  const int qt = lin >> 5;                          // 0..15
  const int qbase = qt * 128 + wv * 16;
  const size_t base = (size_t)bh * S * DH;
  bf16* Pw = (bf16*)(smem + 32768 + wv * 2048);  // [16][64] bf16
  const int xm = (lo & 7) << 1;                  // P-swizzle (8B granules)

  // staging constants: 16 chunks of 1KB (8 K + 8 V), 2 per wave
  const int c0 = wv * 2;
  const int rloc = lane >> 3;
  const int gx = (lane & 7) ^ rloc;
  const int rx = lo & 7;  // read swizzle key

  // Q B-frags: 16 q-rows for this wave
  bf16x8 qf[2];
  {
    const bf16* qp = Qg + base + (size_t)(qbase + lo) * DH + quad * 8;
    qf[0] = *(const bf16x8*)qp;
    qf[1] = *(const bf16x8*)(qp + 32);
  }

  f32x4 Oacc[4];
#pragma unroll
  for (int j = 0; j < 4; j++) Oacc[j] = {0.f, 0.f, 0.f, 0.f};
  f32x2 lp = {0.f, 0.f};

#define STAGE(kt_, buf_)                                                       \
  {                                                                            \
    _Pragma("unroll") for (int j = 0; j < 2; j++) {                            \
      int c = c0 + j;                                                          \
      if (c < 8) {                                                             \
        async16((buf_) + c * 1024,                                             \
                Kg + base + (size_t)((kt_)*64 + c * 8 + rloc) * 64 + gx * 8);  \
      } else {                                                                 \
        int cv = c - 8;                                                        \
        async16((buf_) + 8192 + cv * 1024,                                     \
                VTg + base + (size_t)(cv * 8 + rloc) * S + (kt_)*64 + gx * 8); \
      }                                                                        \
    }                                                                          \
  }

  STAGE(0, smem);
  uint64_t mcur = MB[(size_t)0 * S + qbase + lo];  // prefetched mask word

  for (int kt = 0; kt < 32; ++kt) {
    const char* cur = smem + (kt & 1) * 16384;

    uint64_t m0 = mcur >> (quad * 4);
    uint32_t mw[2] = {(uint32_t)m0, (uint32_t)(m0 >> 32)};

    __syncthreads();  // publishes stage(kt); drains loads issued last iter
    if (kt + 1 < 32) {
      STAGE(kt + 1, smem + ((kt + 1) & 1) * 16384);
      mcur = MB[(size_t)(kt + 1) * S + qbase + lo];  // hidden under compute
    }

    const char* Kls = cur;
    const char* Vls = cur + 8192;

    // S^T = K Q^T
    f32x4 sacc[4];
#pragma unroll
    for (int mi = 0; mi < 4; mi++) sacc[mi] = {0.f, 0.f, 0.f, 0.f};
    __builtin_amdgcn_s_setprio(1);
#pragma unroll
    for (int mi = 0; mi < 4; mi++) {
      bf16x8 k0 = *(const bf16x8*)(Kls + (mi * 16 + lo) * 128 + ((quad ^ rx) * 16));
      bf16x8 k1 = *(const bf16x8*)(Kls + (mi * 16 + lo) * 128 + (((4 + quad) ^ rx) * 16));
      sacc[mi] = __builtin_amdgcn_mfma_f32_16x16x32_bf16(k0, qf[0], sacc[mi], 0, 0, 0);
      sacc[mi] = __builtin_amdgcn_mfma_f32_16x16x32_bf16(k1, qf[1], sacc[mi], 0, 0, 0);
    }
    __builtin_amdgcn_s_setprio(0);

    // p = bit ? exp2(s) : 0 via AND with sign-extended bit (bit-identical,
    // v_bfe_i32+v_and = 2 ops vs bfe+cmp+cndmask = 3); pk-add row sums.
#pragma unroll
    for (int mi = 0; mi < 4; mi++) {
      bf16x4 t;
#pragma unroll
      for (int r = 0; r < 4; r++) {
        float p = __builtin_amdgcn_exp2f(sacc[mi][r]);
        int ext = __builtin_amdgcn_sbfe((int)mw[mi >> 1], ((mi & 1) << 4) + r, 1);
        p = __builtin_bit_cast(float, __builtin_bit_cast(int, p) & ext);
        lp[r & 1] += p;
        t[r] = (bf16)p;
      }
      *(bf16x4*)&Pw[lo * 64 + (((mi * 4 + quad) ^ xm) * 4)] = t;
    }

    // O += P V
    __builtin_amdgcn_s_setprio(1);
#pragma unroll
    for (int kk = 0; kk < 2; kk++) {
      int g16 = kk * 8 + quad * 2;
      bf16x8 pa = *(const bf16x8*)&Pw[lo * 64 + ((g16 ^ xm) * 4)];
#pragma unroll
      for (int ni = 0; ni < 4; ni++) {
        bf16x8 vb = *(const bf16x8*)(Vls + (ni * 16 + lo) * 128 +
                                     (((kk * 4 + quad) ^ rx) * 16));
        Oacc[ni] = __builtin_amdgcn_mfma_f32_16x16x32_bf16(pa, vb, Oacc[ni], 0, 0, 0);
      }
    }
    __builtin_amdgcn_s_setprio(0);
  }
#undef STAGE

  // finish row-sums across quads (keys split 4/quad per mi)
  float lpart = lp[0] + lp[1];
  lpart += __shfl_xor(lpart, 16);
  lpart += __shfl_xor(lpart, 32);

  const int b = bh >> 4, h = bh & (H - 1);
#pragma unroll
  for (int r = 0; r < 4; r++) {
    float inv = 1.0f / __shfl(lpart, quad * 4 + r);
    int q = qbase + quad * 4 + r;
    size_t rowoff = (size_t)(b * S + q) * D + h * DH;
#pragma unroll
    for (int ni = 0; ni < 4; ni++)
      AO[rowoff + ni * 16 + lo] = (f16)(Oacc[ni][r] * inv);
  }
}

// ===================== launch =====================
extern "C" void kernel_launch(void* const* d_in, const int* in_sizes, int n_in,
                              void* d_out, int out_size, void* d_ws,
                              size_t ws_size, hipStream_t stream) {
  const float* q = (const float*)d_in[0];
  const float* k = (const float*)d_in[1];
  const float* v = (const float*)d_in[2];
  const int* mask = (const int*)d_in[3];
  const float* w_q = (const float*)d_in[4];
  const float* b_q = (const float*)d_in[5];
  const float* w_k = (const float*)d_in[6];
  const float* b_k = (const float*)d_in[7];
  const float* w_v = (const float*)d_in[8];
  const float* b_v = (const float*)d_in[9];
  const float* w_o = (const float*)d_in[10];
  const float* b_o = (const float*)d_in[11];

  // ws (MiB offsets):
  // [0,8) Qb | [8,16) Kb | [16,24) VT | [24,32) qA | [32,40) kA | [40,48) vA
  // [48,50) WTq | [50,52) WTk | [52,54) WTv | [54,56) WoT(f16) | [58,58.5) MB
  // overlays: AO(f16)=[24,32) (after gemm_qkv consumes qA)
  char* w = (char*)d_ws;
  const size_t MiB = 1ull << 20;
  bf16* Qb = (bf16*)w;
  bf16* Kb = (bf16*)(w + 8 * MiB);
  bf16* VT = (bf16*)(w + 16 * MiB);
  bf16* qA = (bf16*)(w + 24 * MiB);
  bf16* kA = (bf16*)(w + 32 * MiB);
  bf16* vA = (bf16*)(w + 40 * MiB);
  f16* AO = (f16*)(w + 24 * MiB);
  bf16* WTq = (bf16*)(w + 48 * MiB);
  bf16* WTk = (bf16*)(w + 50 * MiB);
  bf16* WTv = (bf16*)(w + 52 * MiB);
  f16* WoT = (f16*)(w + 54 * MiB);
  uint64_t* MBits = (uint64_t*)(w + 58 * MiB);

  prep<<<29696, 256, 0, stream>>>(mask, MBits, q, k, v, qA, kA, vA, w_q, w_k,
                                  w_v, w_o, WTq, WTk, WTv, WoT);
  gemm_qkv<<<dim3(8, 32, 3), 256, 0, stream>>>(qA, kA, vA, WTq, WTk, WTv, b_q,
                                               b_k, b_v, Qb, Kb, VT);
  attn_kernel<<<dim3(512), 512, 0, stream>>>(Qb, Kb, VT, MBits, AO);
  gemm_o<<<dim3(8, 64), 256, 0, stream>>>(AO, WoT, b_o, (float*)d_out);
}

// Round 12
// 245.778 us; speedup vs baseline: 1.0263x; 1.0095x over previous
//
#include <hip/hip_runtime.h>
#include <stdint.h>

typedef __bf16 bf16;
typedef _Float16 f16;
typedef __attribute__((ext_vector_type(4))) __bf16 bf16x4;
typedef __attribute__((ext_vector_type(8))) __bf16 bf16x8;
typedef __attribute__((ext_vector_type(8))) _Float16 f16x8;
typedef __attribute__((ext_vector_type(4))) float f32x4;
typedef __attribute__((ext_vector_type(2))) float f32x2;
typedef __attribute__((ext_vector_type(2))) unsigned int u32x2;
typedef __attribute__((ext_vector_type(4))) unsigned int u32x4;

constexpr int S = 2048;
constexpr int D = 1024;
constexpr int H = 16;
constexpr int DH = 64;
constexpr int M = 4096;  // B*S

constexpr float QSCALE = 0.18033688011112042f;  // 0.125 * log2(e)

#if __has_builtin(__builtin_amdgcn_permlane32_swap) && \
    __has_builtin(__builtin_amdgcn_permlane16_swap)
#define REG_P 1
#define ATTN_SMEM 32768
#else
#define REG_P 0
#define ATTN_SMEM 49152
#endif

// async global->LDS, 16B/lane; LDS dst = wave-uniform base + lane*16
__device__ __forceinline__ void async16(void* lds, const void* g) {
  __builtin_amdgcn_global_load_lds(
      (const __attribute__((address_space(1))) void*)g,
      (__attribute__((address_space(3))) void*)lds, 16, 0, 0);
}

// ===================== prep: maskbits + cvt3 + wtrans in one launch ==========
__global__ __launch_bounds__(256) void prep(
    const int* __restrict__ mask, uint64_t* __restrict__ MB,
    const float* __restrict__ q, const float* __restrict__ k,
    const float* __restrict__ v, bf16* __restrict__ qA, bf16* __restrict__ kA,
    bf16* __restrict__ vA, const float* __restrict__ Wq,
    const float* __restrict__ Wk, const float* __restrict__ Wv,
    const float* __restrict__ Wo, bf16* __restrict__ WTq,
    bf16* __restrict__ WTk, bf16* __restrict__ WTv, f16* __restrict__ WoT) {
  __shared__ float T[64 * 68];
  const int bid = blockIdx.x;
  const int tid = threadIdx.x;

  if (bid < 16384) {  // ---- maskbits ----
    const int gid = bid * 4 + (tid >> 6);
    const int lane = tid & 63;
    const int kt = gid >> 11;
    const int qq = gid & (S - 1);
    int mv = mask[(size_t)qq * S + kt * 64 + lane];
    uint64_t bits = __ballot(mv != 0);
    if (lane == 0) MB[(size_t)kt * S + qq] = bits;
    return;
  }

  if (bid < 28672) {  // ---- cvt3 ----
    const int idx = bid - 16384;
    const int z = idx >> 12;
    const int x = idx & 4095;
    const float* src = (z == 0) ? q : (z == 1) ? k : v;
    bf16* dst = (z == 0) ? qA : (z == 1) ? kA : vA;
    const size_t i = ((size_t)x * 256 + tid) * 4;
    f32x4 xv = *(const f32x4*)(src + i);
    bf16x4 o;
#pragma unroll
    for (int j = 0; j < 4; j++) o[j] = (bf16)xv[j];
    *(bf16x4*)(dst + i) = o;
    return;
  }

  // ---- wtrans ----
  const int idx = bid - 28672;  // 0..1023
  const int z = idx >> 8;
  const int xy = idx & 255;
  const int n0 = (xy >> 4) * 64, k0 = (xy & 15) * 64;
  const float* W = (z == 0) ? Wq : (z == 1) ? Wk : (z == 2) ? Wv : Wo;
  const int lr = tid >> 4, lc = (tid & 15) * 4;
#pragma unroll
  for (int r = 0; r < 4; r++) {
    f32x4 vv = *(const f32x4*)(W + (size_t)(k0 + r * 16 + lr) * 1024 + n0 + lc);
    *(f32x4*)&T[(r * 16 + lr) * 68 + lc] = vv;
  }
  __syncthreads();
  const int nn = tid >> 3, kc = (tid & 7) * 8;
#pragma unroll
  for (int p = 0; p < 2; p++) {
    int n = p * 32 + nn;
    if (z < 3) {
      bf16x8 h;
#pragma unroll
      for (int j = 0; j < 8; j++) h[j] = (bf16)T[(kc + j) * 68 + n];
      bf16* WT = (z == 0) ? WTq : (z == 1) ? WTk : WTv;
      *(bf16x8*)(WT + (size_t)(n0 + n) * 1024 + k0 + kc) = h;
    } else {
      f16x8 hf;
#pragma unroll
      for (int j = 0; j < 8; j++) hf[j] = (f16)T[(kc + j) * 68 + n];
      *(f16x8*)(WoT + (size_t)(n0 + n) * 1024 + k0 + kc) = hf;
    }
  }
}

// ===================== fused QKV GEMM: BK=32 dbuf prefetch, pair-interleave ====
__global__ __launch_bounds__(256) void gemm_qkv(
    const bf16* __restrict__ Aq, const bf16* __restrict__ Ak,
    const bf16* __restrict__ Av, const bf16* __restrict__ WTq,
    const bf16* __restrict__ WTk, const bf16* __restrict__ WTv,
    const float* __restrict__ bq, const float* __restrict__ bk,
    const float* __restrict__ bv, bf16* __restrict__ Qb,
    bf16* __restrict__ Kb, bf16* __restrict__ VT) {
  __shared__ char smem[34816];  // dbuf [0,32K); epilogue T overlay 34816B

  const int z = blockIdx.z;
  const bf16* A = (z == 0) ? Aq : (z == 1) ? Ak : Av;
  const bf16* WT = (z == 0) ? WTq : (z == 1) ? WTk : WTv;
  const float* bias = (z == 0) ? bq : (z == 1) ? bk : bv;
  const float oscale = (z == 0) ? QSCALE : 1.0f;

  const int tid = threadIdx.x;
  const int bn = blockIdx.x * 128;
  const int bm = blockIdx.y * 128;
  const int wv = tid >> 6;
  const int lane = tid & 63;
  const int quad = lane >> 4;
  const int lo = lane & 15;
  const int wm4 = (wv >> 1) * 4096;  // A row-block byte offset (64 rows)
  const int wn4 = (wv & 1) * 4096;   // B row-block byte offset

  f32x4 acc[4][4];
#pragma unroll
  for (int i = 0; i < 4; i++)
#pragma unroll
    for (int j = 0; j < 4; j++) acc[i][j] = {0.f, 0.f, 0.f, 0.f};

  // pair-interleave staging (chunk = 16 rows = 8 pairs = 1KB)
  const int pl = lane >> 3;            // pair within chunk
  const int uu = lane & 7;             // 16B unit within 128B pair line
  const int srow = pl * 2 + (uu & 1);  // logical row in chunk
  const int sg = (uu >> 1) ^ (pl & 3); // logical granule fetched
  const int uread = (((quad ^ ((lo >> 1) & 3)) << 1) | (lo & 1)) * 16;
  const int aoff = (lo >> 1) * 128 + uread;

#define QSTAGE(kt_, buf_)                                                      \
  {                                                                            \
    _Pragma("unroll") for (int j = 0; j < 4; j++) {                            \
      int c = wv * 4 + j; /* 0..15: 8 A-chunks then 8 B-chunks */              \
      if (c < 8) {                                                             \
        async16((buf_) + c * 1024,                                             \
                A + (size_t)(bm + c * 16 + srow) * 1024 + (kt_)*32 + sg * 8);  \
      } else {                                                                 \
        int cb = c - 8;                                                        \
        async16((buf_) + 8192 + cb * 1024,                                     \
                WT + (size_t)(bn + cb * 16 + srow) * 1024 + (kt_)*32 + sg * 8);\
      }                                                                        \
    }                                                                          \
  }

  QSTAGE(0, smem);

  for (int kt = 0; kt < 32; ++kt) {
    const char* cur = smem + (kt & 1) * 16384;
    __syncthreads();  // publishes stage(kt); drains loads issued last iter
    if (kt + 1 < 32) QSTAGE(kt + 1, smem + ((kt + 1) & 1) * 16384);

    bf16x8 af[4], bfr[4];
#pragma unroll
    for (int mi = 0; mi < 4; mi++)
      af[mi] = *(const bf16x8*)(cur + wm4 + mi * 1024 + aoff);
#pragma unroll
    for (int ni = 0; ni < 4; ni++)
      bfr[ni] = *(const bf16x8*)(cur + 8192 + wn4 + ni * 1024 + aoff);
#pragma unroll
    for (int mi = 0; mi < 4; mi++)
#pragma unroll
      for (int ni = 0; ni < 4; ni++)
        acc[mi][ni] = __builtin_amdgcn_mfma_f32_16x16x32_bf16(
            af[mi], bfr[ni], acc[mi][ni], 0, 0, 0);
  }
#undef QSTAGE

  const int b = bm >> 11;
  const int srow0 = bm & (S - 1);
  const int wm = (wv >> 1) * 64;
  const int wn = (wv & 1) * 64;

  if (z == 2) {  // V^T: direct bf16x4 stores [bh][dh][s]
#pragma unroll
    for (int mi = 0; mi < 4; mi++)
#pragma unroll
      for (int ni = 0; ni < 4; ni++) {
        int col = bn + wn + ni * 16 + lo;
        int h = col >> 6, dh = col & 63;
        float bvv = bias[col];
        bf16x4 t;
#pragma unroll
        for (int r = 0; r < 4; r++) t[r] = (bf16)(acc[mi][ni][r] + bvv);
        int s0 = srow0 + wm + mi * 16 + quad * 4;
        *(bf16x4*)&VT[(((size_t)(b * H + h)) * DH + dh) * S + s0] = t;
      }
    return;
  }

  // Q/K: LDS transpose -> coalesced [bh][s][dh] stores
  __syncthreads();  // all waves done reading dbuf before T overlay
  bf16* T = (bf16*)smem;  // [128][136]
#pragma unroll
  for (int mi = 0; mi < 4; mi++)
#pragma unroll
    for (int ni = 0; ni < 4; ni++) {
      int col = wn + ni * 16 + lo;
      float bvv = bias[bn + col];
#pragma unroll
      for (int r = 0; r < 4; r++) {
        int row = wm + mi * 16 + quad * 4 + r;
        T[row * 136 + col] = (bf16)((acc[mi][ni][r] + bvv) * oscale);
      }
    }
  __syncthreads();
  bf16* out = (z == 0) ? Qb : Kb;
  const int rr = tid >> 1;
  const int half = tid & 1;
  const int h = (bn >> 6) + half;
  bf16* gp = out + (((size_t)(b * H + h)) * S + srow0 + rr) * DH;
#pragma unroll
  for (int j = 0; j < 8; j++)
    *(bf16x8*)(gp + j * 8) = *(const bf16x8*)&T[rr * 136 + half * 64 + j * 8];
}

// ===================== O-projection: fp16 GEMM, 64x128 tiles, 2 blocks/CU ======
__global__ __launch_bounds__(256) void gemm_o(
    const f16* __restrict__ A, const f16* __restrict__ WT,
    const float* __restrict__ bias, float* __restrict__ out) {
  __shared__ char smem[24576];  // A [0,8K) B [8K,24K)

  const int tid = threadIdx.x;
  const int bn = blockIdx.x * 128;
  const int bm = blockIdx.y * 64;
  const int wv = tid >> 6;
  const int lane = tid & 63;
  const int quad = lane >> 4;
  const int lo = lane & 15;
  const int wm = (wv >> 1) * 32;
  const int wn = (wv & 1) * 64;

  f32x4 acc[2][4];
#pragma unroll
  for (int i = 0; i < 2; i++)
#pragma unroll
    for (int j = 0; j < 4; j++) acc[i][j] = {0.f, 0.f, 0.f, 0.f};

  const int rloc = lane >> 3;
  const int gx = (lane & 7) ^ rloc;
  const int rx = (lo & 7);

  for (int kt = 0; kt < 16; ++kt) {
#pragma unroll
    for (int j = 0; j < 2; j++) {  // A: 8 chunks of 8 rows
      int ch = wv * 2 + j;
      async16(smem + ch * 1024,
              A + (size_t)(bm + ch * 8 + rloc) * 1024 + kt * 64 + gx * 8);
    }
#pragma unroll
    for (int j = 0; j < 4; j++) {  // B: 16 chunks of 8 rows
      int ch = wv * 4 + j;
      async16(smem + 8192 + ch * 1024,
              WT + (size_t)(bn + ch * 8 + rloc) * 1024 + kt * 64 + gx * 8);
    }
    __syncthreads();

#pragma unroll
    for (int ks = 0; ks < 2; ks++) {
      f16x8 af[2], bfr[4];
#pragma unroll
      for (int mi = 0; mi < 2; mi++)
        af[mi] = *(const f16x8*)(smem + (wm + mi * 16 + lo) * 128 +
                                 (((ks * 4 + quad) ^ rx) * 16));
#pragma unroll
      for (int ni = 0; ni < 4; ni++)
        bfr[ni] = *(const f16x8*)(smem + 8192 + (wn + ni * 16 + lo) * 128 +
                                  (((ks * 4 + quad) ^ rx) * 16));
#pragma unroll
      for (int mi = 0; mi < 2; mi++)
#pragma unroll
        for (int ni = 0; ni < 4; ni++)
          acc[mi][ni] = __builtin_amdgcn_mfma_f32_16x16x32_f16(
              af[mi], bfr[ni], acc[mi][ni], 0, 0, 0);
    }
    __syncthreads();
  }

#pragma unroll
  for (int mi = 0; mi < 2; mi++)
#pragma unroll
    for (int ni = 0; ni < 4; ni++) {
      int col = bn + wn + ni * 16 + lo;
      float bvv = bias[col];
#pragma unroll
      for (int r = 0; r < 4; r++) {
        int row = bm + wm + mi * 16 + quad * 4 + r;
        out[(size_t)row * 1024 + col] = acc[mi][ni][r] + bvv;
      }
    }
}

// ===================== attention: 8 waves, dbuf K/V, register-P via permlane ==
// QK^T D-layout: lane(lo,quad) holds P^T[k=mi*16+quad*4+r][q=lo], packed as
// u0[mi]=(r0,r1), u1[mi]=(r2,r3). PV A-fragment needs pa dword w at key
// k=kk*32+quad*8+2w from source quad qs=(quad&1)*2+(w>>1), mi=kk*2+(quad>>1).
// Chain p32swap(a,b);p16swap(a,b) (both-written CDNA4 semantics via builtins)
// delivers a={w0|w1}, b={w2|w3} exactly. Fallback: verified LDS P path.
__global__ __launch_bounds__(512) void attn_kernel(
    const bf16* __restrict__ Qg, const bf16* __restrict__ Kg,
    const bf16* __restrict__ VTg, const uint64_t* __restrict__ MB,
    f16* __restrict__ AO) {
  __shared__ char smem[ATTN_SMEM];

  const int tid = threadIdx.x;
  const int wv = tid >> 6;  // 0..7
  const int lane = tid & 63;
  const int quad = lane >> 4;
  const int lo = lane & 15;

  const int lin = blockIdx.x;  // 512 blocks
  const int bh = (lin & 7) * 4 + ((lin >> 3) & 3);  // XCD-local K/V set
  const int qt = lin >> 5;                          // 0..15
  const int qbase = qt * 128 + wv * 16;
  const size_t base = (size_t)bh * S * DH;
#if !REG_P
  bf16* Pw = (bf16*)(smem + 32768 + wv * 2048);  // [16][64] bf16
  const int xm = (lo & 7) << 1;                  // P-swizzle (8B granules)
#endif

  // staging constants: 16 chunks of 1KB (8 K + 8 V), 2 per wave
  const int c0 = wv * 2;
  const int rloc = lane >> 3;
  const int gx = (lane & 7) ^ rloc;
  const int rx = lo & 7;  // read swizzle key

  // Q B-frags: 16 q-rows for this wave
  bf16x8 qf[2];
  {
    const bf16* qp = Qg + base + (size_t)(qbase + lo) * DH + quad * 8;
    qf[0] = *(const bf16x8*)qp;
    qf[1] = *(const bf16x8*)(qp + 32);
  }

  f32x4 Oacc[4];
#pragma unroll
  for (int j = 0; j < 4; j++) Oacc[j] = {0.f, 0.f, 0.f, 0.f};
  f32x2 lp = {0.f, 0.f};

#define STAGE(kt_, buf_)                                                       \
  {                                                                            \
    _Pragma("unroll") for (int j = 0; j < 2; j++) {                            \
      int c = c0 + j;                                                          \
      if (c < 8) {                                                             \
        async16((buf_) + c * 1024,                                             \
                Kg + base + (size_t)((kt_)*64 + c * 8 + rloc) * 64 + gx * 8);  \
      } else {                                                                 \
        int cv = c - 8;                                                        \
        async16((buf_) + 8192 + cv * 1024,                                     \
                VTg + base + (size_t)(cv * 8 + rloc) * S + (kt_)*64 + gx * 8); \
      }                                                                        \
    }                                                                          \
  }

  STAGE(0, smem);
  uint64_t mcur = MB[(size_t)0 * S + qbase + lo];  // prefetched mask word

  for (int kt = 0; kt < 32; ++kt) {
    const char* cur = smem + (kt & 1) * 16384;

    uint64_t m0 = mcur >> (quad * 4);
    uint32_t mw[2] = {(uint32_t)m0, (uint32_t)(m0 >> 32)};

    __syncthreads();  // publishes stage(kt); drains loads issued last iter
    if (kt + 1 < 32) {
      STAGE(kt + 1, smem + ((kt + 1) & 1) * 16384);
      mcur = MB[(size_t)(kt + 1) * S + qbase + lo];  // hidden under compute
    }

    const char* Kls = cur;
    const char* Vls = cur + 8192;

    // S^T = K Q^T
    f32x4 sacc[4];
#pragma unroll
    for (int mi = 0; mi < 4; mi++) sacc[mi] = {0.f, 0.f, 0.f, 0.f};
    __builtin_amdgcn_s_setprio(1);
#pragma unroll
    for (int mi = 0; mi < 4; mi++) {
      bf16x8 k0 = *(const bf16x8*)(Kls + (mi * 16 + lo) * 128 + ((quad ^ rx) * 16));
      bf16x8 k1 = *(const bf16x8*)(Kls + (mi * 16 + lo) * 128 + (((4 + quad) ^ rx) * 16));
      sacc[mi] = __builtin_amdgcn_mfma_f32_16x16x32_bf16(k0, qf[0], sacc[mi], 0, 0, 0);
      sacc[mi] = __builtin_amdgcn_mfma_f32_16x16x32_bf16(k1, qf[1], sacc[mi], 0, 0, 0);
    }
    __builtin_amdgcn_s_setprio(0);

    // p = bit ? exp2(s) : 0 via AND with sign-extended bit (bit-identical);
    // pk-add row sums. Pack p into u0 (r0,r1) / u1 (r2,r3) per mi.
    uint32_t u0[4], u1[4];
#pragma unroll
    for (int mi = 0; mi < 4; mi++) {
      bf16x4 t;
#pragma unroll
      for (int r = 0; r < 4; r++) {
        float p = __builtin_amdgcn_exp2f(sacc[mi][r]);
        int ext = __builtin_amdgcn_sbfe((int)mw[mi >> 1], ((mi & 1) << 4) + r, 1);
        p = __builtin_bit_cast(float, __builtin_bit_cast(int, p) & ext);
        lp[r & 1] += p;
        t[r] = (bf16)p;
      }
#if REG_P
      u32x2 w = __builtin_bit_cast(u32x2, t);
      u0[mi] = w[0];
      u1[mi] = w[1];
#else
      (void)u0;
      (void)u1;
      *(bf16x4*)&Pw[lo * 64 + (((mi * 4 + quad) ^ xm) * 4)] = t;
#endif
    }

    // O += P V
    __builtin_amdgcn_s_setprio(1);
#pragma unroll
    for (int kk = 0; kk < 2; kk++) {
      bf16x8 pa;
#if REG_P
      uint32_t a0 = u0[kk * 2], b0 = u0[kk * 2 + 1];
      uint32_t a1 = u1[kk * 2], b1 = u1[kk * 2 + 1];
      u32x2 r0 = __builtin_amdgcn_permlane32_swap(a0, b0, false, false);
      r0 = __builtin_amdgcn_permlane16_swap(r0[0], r0[1], false, false);
      u32x2 r1 = __builtin_amdgcn_permlane32_swap(a1, b1, false, false);
      r1 = __builtin_amdgcn_permlane16_swap(r1[0], r1[1], false, false);
      u32x4 paw = {r0[0], r1[0], r0[1], r1[1]};  // w0,w1,w2,w3
      pa = __builtin_bit_cast(bf16x8, paw);
#else
      int g16 = kk * 8 + quad * 2;
      pa = *(const bf16x8*)&Pw[lo * 64 + ((g16 ^ xm) * 4)];
#endif
#pragma unroll
      for (int ni = 0; ni < 4; ni++) {
        bf16x8 vb = *(const bf16x8*)(Vls + (ni * 16 + lo) * 128 +
                                     (((kk * 4 + quad) ^ rx) * 16));
        Oacc[ni] = __builtin_amdgcn_mfma_f32_16x16x32_bf16(pa, vb, Oacc[ni], 0, 0, 0);
      }
    }
    __builtin_amdgcn_s_setprio(0);
  }
#undef STAGE

  // finish row-sums across quads (keys split 4/quad per mi)
  float lpart = lp[0] + lp[1];
  lpart += __shfl_xor(lpart, 16);
  lpart += __shfl_xor(lpart, 32);

  const int b = bh >> 4, h = bh & (H - 1);
#pragma unroll
  for (int r = 0; r < 4; r++) {
    float inv = 1.0f / __shfl(lpart, quad * 4 + r);
    int q = qbase + quad * 4 + r;
    size_t rowoff = (size_t)(b * S + q) * D + h * DH;
#pragma unroll
    for (int ni = 0; ni < 4; ni++)
      AO[rowoff + ni * 16 + lo] = (f16)(Oacc[ni][r] * inv);
  }
}

// ===================== launch =====================
extern "C" void kernel_launch(void* const* d_in, const int* in_sizes, int n_in,
                              void* d_out, int out_size, void* d_ws,
                              size_t ws_size, hipStream_t stream) {
  const float* q = (const float*)d_in[0];
  const float* k = (const float*)d_in[1];
  const float* v = (const float*)d_in[2];
  const int* mask = (const int*)d_in[3];
  const float* w_q = (const float*)d_in[4];
  const float* b_q = (const float*)d_in[5];
  const float* w_k = (const float*)d_in[6];
  const float* b_k = (const float*)d_in[7];
  const float* w_v = (const float*)d_in[8];
  const float* b_v = (const float*)d_in[9];
  const float* w_o = (const float*)d_in[10];
  const float* b_o = (const float*)d_in[11];

  // ws (MiB offsets):
  // [0,8) Qb | [8,16) Kb | [16,24) VT | [24,32) qA | [32,40) kA | [40,48) vA
  // [48,50) WTq | [50,52) WTk | [52,54) WTv | [54,56) WoT(f16) | [58,58.5) MB
  // overlays: AO(f16)=[24,32) (after gemm_qkv consumes qA)
  char* w = (char*)d_ws;
  const size_t MiB = 1ull << 20;
  bf16* Qb = (bf16*)w;
  bf16* Kb = (bf16*)(w + 8 * MiB);
  bf16* VT = (bf16*)(w + 16 * MiB);
  bf16* qA = (bf16*)(w + 24 * MiB);
  bf16* kA = (bf16*)(w + 32 * MiB);
  bf16* vA = (bf16*)(w + 40 * MiB);
  f16* AO = (f16*)(w + 24 * MiB);
  bf16* WTq = (bf16*)(w + 48 * MiB);
  bf16* WTk = (bf16*)(w + 50 * MiB);
  bf16* WTv = (bf16*)(w + 52 * MiB);
  f16* WoT = (f16*)(w + 54 * MiB);
  uint64_t* MBits = (uint64_t*)(w + 58 * MiB);

  prep<<<29696, 256, 0, stream>>>(mask, MBits, q, k, v, qA, kA, vA, w_q, w_k,
                                  w_v, w_o, WTq, WTk, WTv, WoT);
  gemm_qkv<<<dim3(8, 32, 3), 256, 0, stream>>>(qA, kA, vA, WTq, WTk, WTv, b_q,
                                               b_k, b_v, Qb, Kb, VT);
  attn_kernel<<<dim3(512), 512, 0, stream>>>(Qb, Kb, VT, MBits, AO);
  gemm_o<<<dim3(8, 64), 256, 0, stream>>>(AO, WoT, b_o, (float*)d_out);
}